// Round 10
// baseline (602.576 us; speedup 1.0000x reference)
//
#include <hip/hip_runtime.h>
#include <stdint.h>

typedef short short8 __attribute__((ext_vector_type(8)));
typedef float floatx4 __attribute__((ext_vector_type(4)));
typedef float f32x2 __attribute__((ext_vector_type(2)));
typedef unsigned int u32x4 __attribute__((ext_vector_type(4)));  // nt-store-compatible

#define BK 256   // nodes per bucket

static __device__ __forceinline__ float bflo(unsigned int u) {
    union { unsigned int i; float f; } v; v.i = u << 16; return v.f;
}
static __device__ __forceinline__ float bfhi(unsigned int u) {
    union { unsigned int i; float f; } v; v.i = u & 0xffff0000u; return v.f;
}
static __device__ __forceinline__ unsigned short f2bf(float f) {
    union { float f; unsigned int i; } v; v.f = f;
    unsigned int u = v.i;
    unsigned int r = u + 0x7fffu + ((u >> 16) & 1u);
    return (unsigned short)(r >> 16);
}
// unpack u32 (2 bf16) -> float2 {lo, hi}; feeds v_pk_add_f32
static __device__ __forceinline__ f32x2 unp2(unsigned int u) {
    union { unsigned int i; float f; } lo, hi;
    lo.i = u << 16; hi.i = u & 0xffff0000u;
    f32x2 r; r.x = lo.f; r.y = hi.f; return r;
}

// ---------------- CSR build (r3-proven chain; zero_cnt merged into wconv) ----------------
// r4: grid.sync ~50us/sync on MI355X -> multi-launch. r6: last-block hist+scan
// merge cost ~10us -> split hist/scanK kept.

__global__ void k_wconv_all(const float* __restrict__ W1, const float* __restrict__ W2,
                            const float* __restrict__ Wf, unsigned short* __restrict__ wb1,
                            unsigned short* __restrict__ wb2, unsigned short* __restrict__ wbf,
                            int* __restrict__ bucket_cnt) {
    int i = blockIdx.x * 256 + threadIdx.x;
    if (i < 512) bucket_cnt[i] = 0;
    if (i < 16384) {
        int k = i >> 7, n = i & 127;
        wb1[n * 128 + k] = f2bf(W1[i]);
    } else if (i < 32768) {
        int j = i - 16384, k = j >> 7, n = j & 127;
        wb2[n * 128 + k] = f2bf(W2[j]);
    } else if (i < 40960) {
        int j = i - 32768, k = j >> 6, n = j & 63;
        wbf[n * 128 + k] = f2bf(Wf[j]);
    }
}

__global__ __launch_bounds__(256) void k_hist(const int* __restrict__ dst, int* bucket_cnt,
                                              int E, int N, int K) {
    __shared__ int h[4][512];
    int t = threadIdx.x, w = t >> 6;
    for (int i = t; i < 4 * 512; i += 256) ((int*)h)[i] = 0;
    __syncthreads();
    int per = (E + gridDim.x - 1) / gridDim.x;
    int lo = blockIdx.x * per, hi = min(lo + per, E);
    for (int e = lo + t; e < hi; e += 256) {
        unsigned int d = (unsigned int)dst[e];
        if (d < (unsigned int)N) atomicAdd(&h[w][d >> 8], 1);
    }
    __syncthreads();
    for (int i = t; i < K; i += 256) {
        int c = h[0][i] + h[1][i] + h[2][i] + h[3][i];
        if (c) atomicAdd(&bucket_cnt[i], c);
    }
}

__global__ void k_scanK(const int* __restrict__ bucket_cnt, int* bucket_off, int* bucket_cur,
                        int* row_start, int K, int N) {
    __shared__ int s[512];
    int t = threadIdx.x;
    int v = (t < K) ? bucket_cnt[t] : 0;
    s[t] = v; __syncthreads();
    for (int off = 1; off < 512; off <<= 1) {
        int x = (t >= off) ? s[t - off] : 0;
        __syncthreads();
        s[t] += x;
        __syncthreads();
    }
    if (t < K) { bucket_off[t] = s[t] - v; bucket_cur[t] = s[t] - v; }
    if (t == K - 1) { bucket_off[K] = s[t]; row_start[N] = s[t]; }
}

__global__ __launch_bounds__(256) void k_binscatter(const int* __restrict__ src,
                                                    const int* __restrict__ dst,
                                                    int* bucket_cur, unsigned int* __restrict__ tmp,
                                                    int E, int N, int K) {
    __shared__ int h[4][512];
    int t = threadIdx.x, w = t >> 6;
    for (int i = t; i < 4 * 512; i += 256) ((int*)h)[i] = 0;
    __syncthreads();
    int per = (E + gridDim.x - 1) / gridDim.x;
    int lo = blockIdx.x * per, hi = min(lo + per, E);
    for (int e = lo + t; e < hi; e += 256) {
        unsigned int d = (unsigned int)dst[e];
        if (d < (unsigned int)N) atomicAdd(&h[w][d >> 8], 1);
    }
    __syncthreads();
    for (int k = t; k < K; k += 256) {
        int c0 = h[0][k], c1 = h[1][k], c2 = h[2][k], c3 = h[3][k];
        int tot = c0 + c1 + c2 + c3;
        int base = tot ? atomicAdd(&bucket_cur[k], tot) : 0;
        h[0][k] = base; h[1][k] = base + c0; h[2][k] = base + c0 + c1;
        h[3][k] = base + c0 + c1 + c2;
    }
    __syncthreads();
    for (int e = lo + t; e < hi; e += 256) {
        unsigned int d = (unsigned int)dst[e];
        if (d < (unsigned int)N) {
            unsigned int sv = (unsigned int)src[e];
            if (sv >= (unsigned int)N) sv = 0;
            int p = atomicAdd(&h[w][d >> 8], 1);
            tmp[p] = (sv << 8) | (d & 255u);
        }
    }
}

__global__ __launch_bounds__(256) void k_fine(const unsigned int* __restrict__ tmp,
                                              const int* __restrict__ bucket_off,
                                              int* __restrict__ row_start, float* __restrict__ dinv,
                                              int* __restrict__ csr, int N) {
    __shared__ int deg4[4][BK];
    __shared__ int scn[BK];
    __shared__ int cur[BK];
    int b = blockIdx.x, t = threadIdx.x, w = t >> 6;
    int lo = bucket_off[b], hi = bucket_off[b + 1];
    for (int i = t; i < 4 * BK; i += 256) ((int*)deg4)[i] = 0;
    __syncthreads();
    for (int e = lo + t; e < hi; e += 256) atomicAdd(&deg4[w][tmp[e] & 255u], 1);
    __syncthreads();
    int v = deg4[0][t] + deg4[1][t] + deg4[2][t] + deg4[3][t];
    scn[t] = v; __syncthreads();
    for (int off = 1; off < 256; off <<= 1) {
        int x = (t >= off) ? scn[t - off] : 0;
        __syncthreads();
        scn[t] += x;
        __syncthreads();
    }
    int rs = lo + scn[t] - v;
    cur[t] = rs;
    int node = b * BK + t;
    if (node < N) { row_start[node] = rs; dinv[node] = rsqrtf((float)(v + 1)); }
    __syncthreads();
    for (int e = lo + t; e < hi; e += 256) {
        unsigned int p = tmp[e];
        int pos = atomicAdd(&cur[p & 255u], 1);
        csr[pos] = (int)(p >> 8);
    }
}

// ---------------- GEMM: out[M,NOUT] = X[M,128] @ W[128,NOUT], K=128 ----------------
// SLICED layout = [8 slices][M nodes][16 ch] bf16 (slice-major; 32B per node-slice).
// XF32: X fp32 row-major. XSLICED: X bf16 sliced. OSLICED: out bf16 sliced.
// OUTF32: out fp32 row-major. Persistent: W staged in LDS once per block.
// (r7-verified, unchanged.)

template <int NOUT, bool SCALE, bool BIAS, bool XF32, bool XSLICED, bool OUTF32, bool OSLICED>
__global__ __launch_bounds__(256, 2) void k_gemm(
    const void* __restrict__ Xv, const unsigned short* __restrict__ Wbf,
    const float* __restrict__ bias, const float* __restrict__ dinv,
    void* __restrict__ outv, int M, int MB) {
    // Wl[n*136 + k]; stride 136 (272B == 4 banks mod 32 -> 2-way conflict = free)
    __shared__ __align__(16) unsigned short Wl[NOUT * 136];
    int t = threadIdx.x;
    for (int c = t; c < NOUT * 16; c += 256) {
        short8 v = *(const short8*)(Wbf + (size_t)c * 8);
        *(short8*)(&Wl[(c >> 4) * 136 + (c & 15) * 8]) = v;
    }
    __syncthreads();

    int wave = t >> 6, lane = t & 63;
    int quad = lane >> 4, l16 = lane & 15;
    constexpr int NT = NOUT / 16;

    for (int mb = blockIdx.x; mb < MB; mb += gridDim.x) {
        int m0 = mb * 64 + wave * 16;
        int mr = m0 + l16;
        int mrc = mr < M ? mr : M - 1;

        floatx4 acc[NT];
#pragma unroll
        for (int i = 0; i < NT; i++) acc[i] = (floatx4){0.f, 0.f, 0.f, 0.f};

#pragma unroll
        for (int kc = 0; kc < 4; kc++) {
            short8 a;
            if (XF32) {
                const float* X = (const float*)Xv;
                const float* p = X + (size_t)mrc * 128 + kc * 32 + quad * 8;
                float4 xa = *(const float4*)p;
                float4 xb = *(const float4*)(p + 4);
                a[0] = (short)f2bf(xa.x); a[1] = (short)f2bf(xa.y);
                a[2] = (short)f2bf(xa.z); a[3] = (short)f2bf(xa.w);
                a[4] = (short)f2bf(xb.x); a[5] = (short)f2bf(xb.y);
                a[6] = (short)f2bf(xb.z); a[7] = (short)f2bf(xb.w);
            } else if (XSLICED) {
                const unsigned short* X = (const unsigned short*)Xv;
                int sl = kc * 2 + (quad >> 1);            // slice of channels kc*32+quad*8
                a = *(const short8*)(X + ((size_t)sl * M + mrc) * 16 + (quad & 1) * 8);
            } else {
                const unsigned short* X = (const unsigned short*)Xv;
                a = *(const short8*)(X + (size_t)mrc * 128 + kc * 32 + quad * 8);
            }
#pragma unroll
            for (int nt = 0; nt < NT; nt++) {
                short8 b = *(const short8*)(&Wl[(nt * 16 + l16) * 136 + kc * 32 + quad * 8]);
                acc[nt] = __builtin_amdgcn_mfma_f32_16x16x32_bf16(a, b, acc[nt], 0, 0, 0);
            }
        }

        // C layout: col = l16 (-> n = nt*16+l16), row (within 16) = quad*4 + i
#pragma unroll
        for (int i = 0; i < 4; i++) {
            int r = m0 + quad * 4 + i;
            if (r >= M) continue;
            float sc = SCALE ? dinv[r] : 1.0f;
#pragma unroll
            for (int nt = 0; nt < NT; nt++) {
                int n = nt * 16 + l16;
                float v = acc[nt][i] * sc;
                if (BIAS) v += bias[n];
                if (OUTF32) {
                    ((float*)outv)[(size_t)r * NOUT + n] = v;
                } else if (OSLICED) {
                    // n>>4 = nt, n&15 = l16
                    ((unsigned short*)outv)[((size_t)nt * M + r) * 16 + l16] = f2bf(v);
                } else {
                    ((unsigned short*)outv)[(size_t)r * NOUT + n] = f2bf(v);
                }
            }
        }
    }
}

// ---------------- Aggregation: XCD-sliced, lane-per-node, L2-protected ----------------
// r8 post-mortem: lane-per-node is VALU-lean (14%) but FETCH exploded 57->283MB:
// the input slice lost L2 residency. Discriminating experiment (r9, repaired for
// the nontemporal-builtin type restriction: clang ext_vector u32x4, not HIP uint4):
//  1. streaming eviction hypothesis: csr loads (6.4MB/XCD stream, zero reuse) and
//     output stores (3.2MB dirty, never re-read here) allocate in L2 and evict
//     the 3.2MB input slice -> csr via __builtin_nontemporal_load, output via
//     __builtin_nontemporal_store.
//  2. csr->gather dependency chain capping MLP -> software-pipeline: iteration
//     k+1's two csr indices load while iteration k's gathers are in flight.
// Pre-committed reads: FETCH ~70-90MB & dur ~35-55us => eviction confirmed;
// FETCH ~283 & dur ~95-105 => chain-only; both ~r8 => decomposition itself is
// the problem -> revert to r7 gather structure next round.

__global__ __launch_bounds__(256, 8) void k_agg_node(
    const unsigned short* __restrict__ Hs, const int* __restrict__ csr,
    const int* __restrict__ row_start, const float* __restrict__ dinv,
    const float* __restrict__ bias, unsigned short* __restrict__ out, int N, int E) {
    int s = blockIdx.x & 7, chunk = blockIdx.x >> 3;
    int node = chunk * 256 + threadIdx.x;
    if (node >= N) return;                    // no cross-lane ops in this kernel
    const unsigned short* Hsl = Hs + (size_t)s * N * 16;
    unsigned short* Osl = out + (size_t)s * N * 16;

    int start = row_start[node];
    int end = row_start[node + 1];
    if (start < 0) start = 0;
    if (end > E) end = E;
    unsigned int Nu = (unsigned int)N;

    f32x2 c0 = {0.f, 0.f}, c1 = {0.f, 0.f}, c2 = {0.f, 0.f}, c3 = {0.f, 0.f};
    f32x2 c4 = {0.f, 0.f}, c5 = {0.f, 0.f}, c6 = {0.f, 0.f}, c7 = {0.f, 0.f};
#define ACCP(ua, ub) do { \
        c0 += unp2((ua).x); c1 += unp2((ua).y); c2 += unp2((ua).z); c3 += unp2((ua).w); \
        c4 += unp2((ub).x); c5 += unp2((ub).y); c6 += unp2((ub).z); c7 += unp2((ub).w); } while (0)

    // software-pipelined 2-edge loop: csr indices for iteration k+1 load (nt)
    // while iteration k's 4 row-gathers are outstanding.
    int e = start;
    int i0 = (e     < end) ? __builtin_nontemporal_load(&csr[e])     : 0;
    int i1 = (e + 1 < end) ? __builtin_nontemporal_load(&csr[e + 1]) : 0;
    for (; e + 2 <= end; e += 2) {
        int n0 = (e + 2 < end) ? __builtin_nontemporal_load(&csr[e + 2]) : 0;
        int n1 = (e + 3 < end) ? __builtin_nontemporal_load(&csr[e + 3]) : 0;
        unsigned int u0 = (unsigned int)i0, u1 = (unsigned int)i1;
        if (u0 >= Nu) u0 = 0;
        if (u1 >= Nu) u1 = 0;
        const uint4* p0 = (const uint4*)(Hsl + (size_t)u0 * 16);
        const uint4* p1 = (const uint4*)(Hsl + (size_t)u1 * 16);
        uint4 a0 = p0[0], b0 = p0[1];
        uint4 a1 = p1[0], b1 = p1[1];
        ACCP(a0, b0);
        ACCP(a1, b1);
        i0 = n0; i1 = n1;
    }
    if (e < end) {                            // tail edge: index already in i0
        unsigned int u0 = (unsigned int)i0;
        if (u0 >= Nu) u0 = 0;
        const uint4* p0 = (const uint4*)(Hsl + (size_t)u0 * 16);
        uint4 a0 = p0[0], b0 = p0[1];
        ACCP(a0, b0);
    }
    // self-loop (cached load: it's in the resident slice)
    {
        const uint4* sp = (const uint4*)(Hsl + (size_t)node * 16);
        uint4 sa = sp[0], sb = sp[1];
        ACCP(sa, sb);
    }
#undef ACCP

    // epilogue: dinv scale + bias + relu, pack 16 bf16, 2 NONTEMPORAL 16B stores
    float di = dinv[node];
    const float* bsl = bias + s * 16;
    float4 q0 = *(const float4*)(bsl);
    float4 q1 = *(const float4*)(bsl + 4);
    float4 q2 = *(const float4*)(bsl + 8);
    float4 q3 = *(const float4*)(bsl + 12);
    float r0  = fmaxf(fmaf(di, c0.x, q0.x), 0.f);
    float r1  = fmaxf(fmaf(di, c0.y, q0.y), 0.f);
    float r2  = fmaxf(fmaf(di, c1.x, q0.z), 0.f);
    float r3  = fmaxf(fmaf(di, c1.y, q0.w), 0.f);
    float r4  = fmaxf(fmaf(di, c2.x, q1.x), 0.f);
    float r5  = fmaxf(fmaf(di, c2.y, q1.y), 0.f);
    float r6  = fmaxf(fmaf(di, c3.x, q1.z), 0.f);
    float r7  = fmaxf(fmaf(di, c3.y, q1.w), 0.f);
    float r8  = fmaxf(fmaf(di, c4.x, q2.x), 0.f);
    float r9  = fmaxf(fmaf(di, c4.y, q2.y), 0.f);
    float r10 = fmaxf(fmaf(di, c5.x, q2.z), 0.f);
    float r11 = fmaxf(fmaf(di, c5.y, q2.w), 0.f);
    float r12 = fmaxf(fmaf(di, c6.x, q3.x), 0.f);
    float r13 = fmaxf(fmaf(di, c6.y, q3.y), 0.f);
    float r14 = fmaxf(fmaf(di, c7.x, q3.z), 0.f);
    float r15 = fmaxf(fmaf(di, c7.y, q3.w), 0.f);
    u32x4 o0, o1;
    o0.x = (unsigned int)f2bf(r0)  | ((unsigned int)f2bf(r1)  << 16);
    o0.y = (unsigned int)f2bf(r2)  | ((unsigned int)f2bf(r3)  << 16);
    o0.z = (unsigned int)f2bf(r4)  | ((unsigned int)f2bf(r5)  << 16);
    o0.w = (unsigned int)f2bf(r6)  | ((unsigned int)f2bf(r7)  << 16);
    o1.x = (unsigned int)f2bf(r8)  | ((unsigned int)f2bf(r9)  << 16);
    o1.y = (unsigned int)f2bf(r10) | ((unsigned int)f2bf(r11) << 16);
    o1.z = (unsigned int)f2bf(r12) | ((unsigned int)f2bf(r13) << 16);
    o1.w = (unsigned int)f2bf(r14) | ((unsigned int)f2bf(r15) << 16);
    __builtin_nontemporal_store(o0, (u32x4*)(Osl + (size_t)node * 16));
    __builtin_nontemporal_store(o1, (u32x4*)(Osl + (size_t)node * 16 + 8));
}

// ---------------- launch ----------------

extern "C" void kernel_launch(void* const* d_in, const int* in_sizes, int n_in,
                              void* d_out, int out_size, void* d_ws, size_t ws_size,
                              hipStream_t stream) {
    const float* x  = (const float*)d_in[0];
    const int* ei   = (const int*)d_in[1];
    const float* W1 = (const float*)d_in[2];
    const float* b1 = (const float*)d_in[3];
    const float* W2 = (const float*)d_in[4];
    const float* b2 = (const float*)d_in[5];
    const float* Wf = (const float*)d_in[6];
    const float* bf = (const float*)d_in[7];

    int N = in_sizes[0] / 128;
    int E = in_sizes[1] / 2;
    const int* src = ei;
    const int* dst = ei + E;
    int K = (N + BK - 1) / BK;
    if (N >= (1 << 24) || K > 512) return;  // packing/scan assumptions

    size_t need = 0;
    auto pad = [](size_t b) { return (b + 255) & ~(size_t)255; };
    size_t o_bcnt = need; need += pad(512 * 4);
    size_t o_boff = need; need += pad(513 * 4);
    size_t o_bcur = need; need += pad(512 * 4);
    size_t o_rs   = need; need += pad(((size_t)N + 1) * 4);
    size_t o_dinv = need; need += pad((size_t)N * 4);
    size_t o_wbf  = need; need += pad((16384 + 16384 + 8192) * 2);
    size_t o_csr  = need; need += pad((size_t)E * 4);
    size_t o_hs   = need; need += pad((size_t)N * 128 * 2);
    size_t o_a    = need; need += pad((size_t)N * 128 * 2);
    if (ws_size < need) return;
    if ((size_t)E * 4 > (size_t)N * 128 * 2) return;  // tmp must fit in A alias

    char* ws = (char*)d_ws;
    int* bucket_cnt = (int*)(ws + o_bcnt);
    int* bucket_off = (int*)(ws + o_boff);
    int* bucket_cur = (int*)(ws + o_bcur);
    int* row_start  = (int*)(ws + o_rs);
    float* dinv     = (float*)(ws + o_dinv);
    unsigned short* wb1 = (unsigned short*)(ws + o_wbf);
    unsigned short* wb2 = wb1 + 16384;
    unsigned short* wbf = wb2 + 16384;
    int* csr        = (int*)(ws + o_csr);
    unsigned short* Hs = (unsigned short*)(ws + o_hs);   // sliced [8][N][16]
    unsigned short* A  = (unsigned short*)(ws + o_a);    // sliced [8][N][16]
    unsigned int* tmp  = (unsigned int*)A;  // alias: tmp dead before A's first write

    // ---- CSR build (5 launches, r3-proven) ----
    k_wconv_all<<<160, 256, 0, stream>>>(W1, W2, Wf, wb1, wb2, wbf, bucket_cnt);
    k_hist<<<256, 256, 0, stream>>>(dst, bucket_cnt, E, N, K);
    k_scanK<<<1, 512, 0, stream>>>(bucket_cnt, bucket_off, bucket_cur, row_start, K, N);
    k_binscatter<<<256, 256, 0, stream>>>(src, dst, bucket_cur, tmp, E, N, K);
    k_fine<<<K, 256, 0, stream>>>(tmp, bucket_off, row_start, dinv, csr, N);

    int MB = (N + 63) / 64;
    int GG = (MB + 1) / 2;          // persistent: 2 row-tiles per block
    int AGG = ((N + 255) / 256) * 8;  // 8 slice-blocks per 256-node chunk

    // layer 1: Hs(sliced) = dinv * (x @ W1)
    k_gemm<128, true, false, true, false, false, true><<<GG, 256, 0, stream>>>(
        x, wb1, nullptr, dinv, Hs, N, MB);
    // agg1: A(sliced) = relu(dinv*(Hs + sum Hs[src]) + b1)
    k_agg_node<<<AGG, 256, 0, stream>>>(Hs, csr, row_start, dinv, b1, A, N, E);
    // layer 2: Hs(sliced) = dinv * (A @ W2)
    k_gemm<128, true, false, false, true, false, true><<<GG, 256, 0, stream>>>(
        A, wb2, nullptr, dinv, Hs, N, MB);
    // agg2: A(sliced) = relu(dinv*(Hs + sum Hs2[src]) + b2)
    k_agg_node<<<AGG, 256, 0, stream>>>(Hs, csr, row_start, dinv, b2, A, N, E);
    // final: out(fp32 row-major) = A @ Wf + bf
    k_gemm<64, false, true, false, true, true, false><<<GG, 256, 0, stream>>>(
        A, wbf, bf, nullptr, d_out, N, MB);
}

// Round 11
// 325.427 us; speedup vs baseline: 1.8516x; 1.8516x over previous
//
#include <hip/hip_runtime.h>
#include <stdint.h>

typedef short short8 __attribute__((ext_vector_type(8)));
typedef float floatx4 __attribute__((ext_vector_type(4)));
typedef float f32x2 __attribute__((ext_vector_type(2)));

#define BK 256   // nodes per bucket

static __device__ __forceinline__ float bflo(unsigned int u) {
    union { unsigned int i; float f; } v; v.i = u << 16; return v.f;
}
static __device__ __forceinline__ float bfhi(unsigned int u) {
    union { unsigned int i; float f; } v; v.i = u & 0xffff0000u; return v.f;
}
static __device__ __forceinline__ unsigned short f2bf(float f) {
    union { float f; unsigned int i; } v; v.f = f;
    unsigned int u = v.i;
    unsigned int r = u + 0x7fffu + ((u >> 16) & 1u);
    return (unsigned short)(r >> 16);
}
// unpack u32 (2 bf16) -> float2 {lo, hi}; feeds v_pk_add_f32
static __device__ __forceinline__ f32x2 unp2(unsigned int u) {
    union { unsigned int i; float f; } lo, hi;
    lo.i = u << 16; hi.i = u & 0xffff0000u;
    f32x2 r; r.x = lo.f; r.y = hi.f; return r;
}

// ---------------- CSR build: two-level counting sort, packed 4B entries ----------------
// Session lessons baked in: grid.sync ~50us/sync on MI355X (r4) -> multi-launch;
// last-block hist+scan merge costs ~10us (r6) -> split hist/scanK; zero_cnt merged
// into wconv (r5+, verified r7-r10). Sliced/NT variants (r7-r10) all lost to this.

// W pre-convert fp32 [K][Nc] -> bf16 transposed [Nc][K]; also zeroes bucket_cnt
// (ordered before k_hist by the launch boundary).
__global__ void k_wconv_all(const float* __restrict__ W1, const float* __restrict__ W2,
                            const float* __restrict__ Wf, unsigned short* __restrict__ wb1,
                            unsigned short* __restrict__ wb2, unsigned short* __restrict__ wbf,
                            int* __restrict__ bucket_cnt) {
    int i = blockIdx.x * 256 + threadIdx.x;
    if (i < 512) bucket_cnt[i] = 0;
    if (i < 16384) {
        int k = i >> 7, n = i & 127;
        wb1[n * 128 + k] = f2bf(W1[i]);
    } else if (i < 32768) {
        int j = i - 16384, k = j >> 7, n = j & 127;
        wb2[n * 128 + k] = f2bf(W2[j]);
    } else if (i < 40960) {
        int j = i - 32768, k = j >> 6, n = j & 63;
        wbf[n * 128 + k] = f2bf(Wf[j]);
    }
}

// coarse histogram of dst>>8; per-wave LDS hists cut same-address contention
__global__ __launch_bounds__(256) void k_hist(const int* __restrict__ dst, int* bucket_cnt,
                                              int E, int N, int K) {
    __shared__ int h[4][512];
    int t = threadIdx.x, w = t >> 6;
    for (int i = t; i < 4 * 512; i += 256) ((int*)h)[i] = 0;
    __syncthreads();
    int per = (E + gridDim.x - 1) / gridDim.x;
    int lo = blockIdx.x * per, hi = min(lo + per, E);
    for (int e = lo + t; e < hi; e += 256) {
        unsigned int d = (unsigned int)dst[e];
        if (d < (unsigned int)N) atomicAdd(&h[w][d >> 8], 1);
    }
    __syncthreads();
    for (int i = t; i < K; i += 256) {
        int c = h[0][i] + h[1][i] + h[2][i] + h[3][i];
        if (c) atomicAdd(&bucket_cnt[i], c);
    }
}

// single block: exclusive scan of K bucket counts (K <= 512); sentinel row_start[N]
__global__ void k_scanK(const int* __restrict__ bucket_cnt, int* bucket_off, int* bucket_cur,
                        int* row_start, int K, int N) {
    __shared__ int s[512];
    int t = threadIdx.x;
    int v = (t < K) ? bucket_cnt[t] : 0;
    s[t] = v; __syncthreads();
    for (int off = 1; off < 512; off <<= 1) {
        int x = (t >= off) ? s[t - off] : 0;
        __syncthreads();
        s[t] += x;
        __syncthreads();
    }
    if (t < K) { bucket_off[t] = s[t] - v; bucket_cur[t] = s[t] - v; }
    if (t == K - 1) { bucket_off[K] = s[t]; row_start[N] = s[t]; }
}

// bucket-sort edges into packed 4B entries (src<<8)|(dst&255); per-wave hists/cursors
__global__ __launch_bounds__(256) void k_binscatter(const int* __restrict__ src,
                                                    const int* __restrict__ dst,
                                                    int* bucket_cur, unsigned int* __restrict__ tmp,
                                                    int E, int N, int K) {
    __shared__ int h[4][512];
    int t = threadIdx.x, w = t >> 6;
    for (int i = t; i < 4 * 512; i += 256) ((int*)h)[i] = 0;
    __syncthreads();
    int per = (E + gridDim.x - 1) / gridDim.x;
    int lo = blockIdx.x * per, hi = min(lo + per, E);
    for (int e = lo + t; e < hi; e += 256) {
        unsigned int d = (unsigned int)dst[e];
        if (d < (unsigned int)N) atomicAdd(&h[w][d >> 8], 1);
    }
    __syncthreads();
    for (int k = t; k < K; k += 256) {
        int c0 = h[0][k], c1 = h[1][k], c2 = h[2][k], c3 = h[3][k];
        int tot = c0 + c1 + c2 + c3;
        int base = tot ? atomicAdd(&bucket_cur[k], tot) : 0;
        h[0][k] = base; h[1][k] = base + c0; h[2][k] = base + c0 + c1;
        h[3][k] = base + c0 + c1 + c2;
    }
    __syncthreads();
    for (int e = lo + t; e < hi; e += 256) {
        unsigned int d = (unsigned int)dst[e];
        if (d < (unsigned int)N) {
            unsigned int sv = (unsigned int)src[e];
            if (sv >= (unsigned int)N) sv = 0;
            int p = atomicAdd(&h[w][d >> 8], 1);
            tmp[p] = (sv << 8) | (d & 255u);
        }
    }
}

// one block per bucket: degrees (per-wave hists) -> scan -> dst-sorted csr + dinv
__global__ __launch_bounds__(256) void k_fine(const unsigned int* __restrict__ tmp,
                                              const int* __restrict__ bucket_off,
                                              int* __restrict__ row_start, float* __restrict__ dinv,
                                              int* __restrict__ csr, int N) {
    __shared__ int deg4[4][BK];
    __shared__ int scn[BK];
    __shared__ int cur[BK];
    int b = blockIdx.x, t = threadIdx.x, w = t >> 6;
    int lo = bucket_off[b], hi = bucket_off[b + 1];
    for (int i = t; i < 4 * BK; i += 256) ((int*)deg4)[i] = 0;
    __syncthreads();
    for (int e = lo + t; e < hi; e += 256) atomicAdd(&deg4[w][tmp[e] & 255u], 1);
    __syncthreads();
    int v = deg4[0][t] + deg4[1][t] + deg4[2][t] + deg4[3][t];
    scn[t] = v; __syncthreads();
    for (int off = 1; off < 256; off <<= 1) {
        int x = (t >= off) ? scn[t - off] : 0;
        __syncthreads();
        scn[t] += x;
        __syncthreads();
    }
    int rs = lo + scn[t] - v;
    cur[t] = rs;
    int node = b * BK + t;
    if (node < N) { row_start[node] = rs; dinv[node] = rsqrtf((float)(v + 1)); }
    __syncthreads();
    for (int e = lo + t; e < hi; e += 256) {
        unsigned int p = tmp[e];
        int pos = atomicAdd(&cur[p & 255u], 1);
        csr[pos] = (int)(p >> 8);
    }
}

// ---------------- GEMM: out[M,NOUT] = X[M,128] @ W[128,NOUT], K=128 ----------------
// Wbf bf16 pre-transposed [NOUT][128]. X fp32 row-major (XF32) or bf16 row-major.
// Out bf16 row-major or fp32 row-major (OUTF32). Persistent: W staged once per block.

template <int NOUT, bool SCALE, bool BIAS, bool XF32, bool OUTF32>
__global__ __launch_bounds__(256, 2) void k_gemm(
    const void* __restrict__ Xv, const unsigned short* __restrict__ Wbf,
    const float* __restrict__ bias, const float* __restrict__ dinv,
    void* __restrict__ outv, int M, int MB) {
    // Wl[n*136 + k]; stride 136 (272B == 4 banks mod 32 -> 2-way conflict = free)
    __shared__ __align__(16) unsigned short Wl[NOUT * 136];
    int t = threadIdx.x;
    for (int c = t; c < NOUT * 16; c += 256) {
        short8 v = *(const short8*)(Wbf + (size_t)c * 8);
        *(short8*)(&Wl[(c >> 4) * 136 + (c & 15) * 8]) = v;
    }
    __syncthreads();

    int wave = t >> 6, lane = t & 63;
    int quad = lane >> 4, l16 = lane & 15;
    constexpr int NT = NOUT / 16;

    for (int mb = blockIdx.x; mb < MB; mb += gridDim.x) {
        int m0 = mb * 64 + wave * 16;
        int mr = m0 + l16;
        int mrc = mr < M ? mr : M - 1;

        floatx4 acc[NT];
#pragma unroll
        for (int i = 0; i < NT; i++) acc[i] = (floatx4){0.f, 0.f, 0.f, 0.f};

#pragma unroll
        for (int kc = 0; kc < 4; kc++) {
            short8 a;
            if (XF32) {
                const float* X = (const float*)Xv;
                const float* p = X + (size_t)mrc * 128 + kc * 32 + quad * 8;
                float4 xa = *(const float4*)p;
                float4 xb = *(const float4*)(p + 4);
                a[0] = (short)f2bf(xa.x); a[1] = (short)f2bf(xa.y);
                a[2] = (short)f2bf(xa.z); a[3] = (short)f2bf(xa.w);
                a[4] = (short)f2bf(xb.x); a[5] = (short)f2bf(xb.y);
                a[6] = (short)f2bf(xb.z); a[7] = (short)f2bf(xb.w);
            } else {
                const unsigned short* X = (const unsigned short*)Xv;
                a = *(const short8*)(X + (size_t)mrc * 128 + kc * 32 + quad * 8);
            }
#pragma unroll
            for (int nt = 0; nt < NT; nt++) {
                short8 b = *(const short8*)(&Wl[(nt * 16 + l16) * 136 + kc * 32 + quad * 8]);
                acc[nt] = __builtin_amdgcn_mfma_f32_16x16x32_bf16(a, b, acc[nt], 0, 0, 0);
            }
        }

        // C layout: col = l16, row (within 16) = quad*4 + i
#pragma unroll
        for (int i = 0; i < 4; i++) {
            int r = m0 + quad * 4 + i;
            if (r >= M) continue;
            float sc = SCALE ? dinv[r] : 1.0f;
#pragma unroll
            for (int nt = 0; nt < NT; nt++) {
                int n = nt * 16 + l16;
                float v = acc[nt][i] * sc;
                if (BIAS) v += bias[n];
                if (OUTF32) {
                    ((float*)outv)[(size_t)r * NOUT + n] = v;
                } else {
                    ((unsigned short*)outv)[(size_t)r * NOUT + n] = f2bf(v);
                }
            }
        }
    }
}

// ---------------- Aggregation: 2 nodes per wave (r3-verified best: 59us) ----------------
// out[d] = relu(dinv[d]*(Hs[d] + sum_nbr Hs[src]) + b).
// Each 32-lane HALF of the wave owns one node; grp = edge-slot, c16 = channel chunk.
// At the measured random-gather pattern ceiling: 187MB L2-fill @ ~3.6 TB/s,
// insensitive to VALU count (r3), MLP depth (r2), occupancy (r6). Sliced/NT
// alternatives (r7-r10) all slower end-to-end.
// shfl discipline: every shfl executes with ALL 64 lanes active; sources stay
// within the issuing 32-lane half (round-1 lesson).

__global__ __launch_bounds__(256, 8) void k_aggregate(
    const unsigned short* __restrict__ Hs, const int* __restrict__ csr,
    const int* __restrict__ row_start,
    const float* __restrict__ dinv, const float* __restrict__ bias,
    unsigned short* __restrict__ out, int N, int E) {
    int wave = threadIdx.x >> 6, lane = threadIdx.x & 63;
    int half = lane >> 5;           // which node of the pair
    int grp = (lane >> 4) & 1;      // edge-slot group within the node
    int c16 = lane & 15;            // channel chunk
    int l32 = lane & 31;            // slot-index space within the node
    int sbase = half << 5;          // shfl source base for this half
    int node = blockIdx.x * 8 + wave * 2 + half;
    int Nm1 = N - 1;
    int node_c = node < N ? node : Nm1;   // clamp: no per-half early return possible
    unsigned int cb2 = (unsigned int)c16 << 4;  // byte offset of the 16B chunk
    const char* Hb = (const char*)Hs;

    int start = row_start[node_c];
    int end = row_start[node_c + 1];
    if (start < 0) start = 0;
    if (end > E) end = E;
    int cnt = end - start;
    if (cnt < 0) cnt = 0;

    // self-loop row: independent load, issued early
    uint4 us = *(const uint4*)(Hb + (((size_t)node_c << 8) | cb2));

    // prefetch up to 32 neighbor indices per node in one coalesced load, clamp once
    int pre = cnt < 32 ? cnt : 32;
    int idxv = 0;
    if (l32 < pre) idxv = min(max(csr[start + l32], 0), Nm1);

    f32x2 a01 = {0.f, 0.f}, a23 = {0.f, 0.f}, a45 = {0.f, 0.f}, a67 = {0.f, 0.f};
#define ACC8(u) do { a01 += unp2((u).x); a23 += unp2((u).y); \
                     a45 += unp2((u).z); a67 += unp2((u).w); } while (0)

    int full2 = pre >> 1;
    int it = 0;
    for (; it + 4 <= full2; it += 4) {  // sources all within own half
        int p = it * 2 + grp;
        int i0 = __shfl(idxv, sbase + p);
        int i1 = __shfl(idxv, sbase + p + 2);
        int i2 = __shfl(idxv, sbase + p + 4);
        int i3 = __shfl(idxv, sbase + p + 6);
        uint4 u0 = *(const uint4*)(Hb + (((unsigned int)i0 << 8) | cb2));
        uint4 u1 = *(const uint4*)(Hb + (((unsigned int)i1 << 8) | cb2));
        uint4 u2 = *(const uint4*)(Hb + (((unsigned int)i2 << 8) | cb2));
        uint4 u3 = *(const uint4*)(Hb + (((unsigned int)i3 << 8) | cb2));
        ACC8(u0); ACC8(u1); ACC8(u2); ACC8(u3);
    }
    for (; it < full2; it++) {
        int i0 = __shfl(idxv, sbase + it * 2 + grp);
        uint4 u0 = *(const uint4*)(Hb + (((unsigned int)i0 << 8) | cb2));
        ACC8(u0);
    }
    // tail (odd pre): shfl outside the divergent branch, clamped source in own half
    int eT = full2 * 2 + grp;
    int iT = __shfl(idxv, sbase + (eT < pre ? eT : 0));
    if (eT < pre) {
        uint4 u0 = *(const uint4*)(Hb + (((unsigned int)iT << 8) | cb2));
        ACC8(u0);
    }
    // overflow (degree > 32, ~1e-5 of nodes): direct csr loads, no shfl
    for (int e = start + 32 + grp; e < end; e += 2) {
        int ii = min(max(csr[e], 0), Nm1);
        uint4 u = *(const uint4*)(Hb + (((unsigned int)ii << 8) | cb2));
        ACC8(u);
    }
#undef ACC8

    float a0 = a01.x, a1 = a01.y, a2 = a23.x, a3 = a23.y;
    float a4 = a45.x, a5 = a45.y, a6 = a67.x, a7 = a67.y;

    // reduce the 2 edge groups: lanes l <-> l^16 stay within the same half
    a0 += __shfl_xor(a0, 16); a1 += __shfl_xor(a1, 16); a2 += __shfl_xor(a2, 16);
    a3 += __shfl_xor(a3, 16); a4 += __shfl_xor(a4, 16); a5 += __shfl_xor(a5, 16);
    a6 += __shfl_xor(a6, 16); a7 += __shfl_xor(a7, 16);

    // self-loop + epilogue (both groups compute; grp 0 of each half stores)
    a0 += bflo(us.x); a1 += bfhi(us.x); a2 += bflo(us.y); a3 += bfhi(us.y);
    a4 += bflo(us.z); a5 += bfhi(us.z); a6 += bflo(us.w); a7 += bfhi(us.w);

    float di = dinv[node_c];
    float4 b0 = *(const float4*)(bias + c16 * 8);
    float4 b1 = *(const float4*)(bias + c16 * 8 + 4);
    float r0 = fmaxf(fmaf(di, a0, b0.x), 0.f);
    float r1 = fmaxf(fmaf(di, a1, b0.y), 0.f);
    float r2 = fmaxf(fmaf(di, a2, b0.z), 0.f);
    float r3 = fmaxf(fmaf(di, a3, b0.w), 0.f);
    float r4 = fmaxf(fmaf(di, a4, b1.x), 0.f);
    float r5 = fmaxf(fmaf(di, a5, b1.y), 0.f);
    float r6 = fmaxf(fmaf(di, a6, b1.z), 0.f);
    float r7 = fmaxf(fmaf(di, a7, b1.w), 0.f);
    if (grp == 0 && node < N) {
        uint4 o;
        o.x = (unsigned int)f2bf(r0) | ((unsigned int)f2bf(r1) << 16);
        o.y = (unsigned int)f2bf(r2) | ((unsigned int)f2bf(r3) << 16);
        o.z = (unsigned int)f2bf(r4) | ((unsigned int)f2bf(r5) << 16);
        o.w = (unsigned int)f2bf(r6) | ((unsigned int)f2bf(r7) << 16);
        *(uint4*)(out + (((size_t)node << 7) | (size_t)(c16 * 8))) = o;
    }
}

// ---------------- launch ----------------

extern "C" void kernel_launch(void* const* d_in, const int* in_sizes, int n_in,
                              void* d_out, int out_size, void* d_ws, size_t ws_size,
                              hipStream_t stream) {
    const float* x  = (const float*)d_in[0];
    const int* ei   = (const int*)d_in[1];
    const float* W1 = (const float*)d_in[2];
    const float* b1 = (const float*)d_in[3];
    const float* W2 = (const float*)d_in[4];
    const float* b2 = (const float*)d_in[5];
    const float* Wf = (const float*)d_in[6];
    const float* bf = (const float*)d_in[7];

    int N = in_sizes[0] / 128;
    int E = in_sizes[1] / 2;
    const int* src = ei;
    const int* dst = ei + E;
    int K = (N + BK - 1) / BK;
    if (N >= (1 << 24) || K > 512) return;  // packing/scan assumptions

    size_t need = 0;
    auto pad = [](size_t b) { return (b + 255) & ~(size_t)255; };
    size_t o_bcnt = need; need += pad(512 * 4);
    size_t o_boff = need; need += pad(513 * 4);
    size_t o_bcur = need; need += pad(512 * 4);
    size_t o_rs   = need; need += pad(((size_t)N + 1) * 4);
    size_t o_dinv = need; need += pad((size_t)N * 4);
    size_t o_wbf  = need; need += pad((16384 + 16384 + 8192) * 2);
    size_t o_csr  = need; need += pad((size_t)E * 4);
    size_t o_hs   = need; need += pad((size_t)N * 128 * 2);
    size_t o_a    = need; need += pad((size_t)N * 128 * 2);
    if (ws_size < need) return;
    if ((size_t)E * 4 > (size_t)N * 128 * 2) return;  // tmp must fit in A alias

    char* ws = (char*)d_ws;
    int* bucket_cnt = (int*)(ws + o_bcnt);
    int* bucket_off = (int*)(ws + o_boff);
    int* bucket_cur = (int*)(ws + o_bcur);
    int* row_start  = (int*)(ws + o_rs);
    float* dinv     = (float*)(ws + o_dinv);
    unsigned short* wb1 = (unsigned short*)(ws + o_wbf);
    unsigned short* wb2 = wb1 + 16384;
    unsigned short* wbf = wb2 + 16384;
    int* csr        = (int*)(ws + o_csr);
    unsigned short* Hs = (unsigned short*)(ws + o_hs);
    unsigned short* A  = (unsigned short*)(ws + o_a);
    unsigned int* tmp  = (unsigned int*)A;  // alias: tmp dead before A's first write

    // ---- CSR build (5 launches; zero_cnt merged into wconv) ----
    k_wconv_all<<<160, 256, 0, stream>>>(W1, W2, Wf, wb1, wb2, wbf, bucket_cnt);
    k_hist<<<256, 256, 0, stream>>>(dst, bucket_cnt, E, N, K);
    k_scanK<<<1, 512, 0, stream>>>(bucket_cnt, bucket_off, bucket_cur, row_start, K, N);
    k_binscatter<<<256, 256, 0, stream>>>(src, dst, bucket_cur, tmp, E, N, K);
    k_fine<<<K, 256, 0, stream>>>(tmp, bucket_off, row_start, dinv, csr, N);

    int MB = (N + 63) / 64;
    int GG = (MB + 1) / 2;  // persistent: 2 row-tiles per block

    k_gemm<128, true, false, true, false><<<GG, 256, 0, stream>>>(x, wb1, nullptr, dinv, Hs, N, MB);
    k_aggregate<<<(N + 7) / 8, 256, 0, stream>>>(Hs, csr, row_start, dinv, b1, A, N, E);
    k_gemm<128, true, false, false, false><<<GG, 256, 0, stream>>>(A, wb2, nullptr, dinv, Hs, N, MB);
    k_aggregate<<<(N + 7) / 8, 256, 0, stream>>>(Hs, csr, row_start, dinv, b2, A, N, E);
    k_gemm<64, false, true, false, true><<<GG, 256, 0, stream>>>(A, wbf, bf, nullptr, d_out, N, MB);
}